// Round 16
// baseline (352.330 us; speedup 1.0000x reference)
//
#include <hip/hip_runtime.h>
#include <stdint.h>

typedef unsigned int u32;
typedef unsigned long long u64;
typedef long long i64;

#define NCLS 81
#define KTOP 1000
#define DETS 100
#define CANDCAP 2048
#define BIGCAP 131072
#define TPB 256
#define RCH 64            // rows per staging chunk: 64*81*4 = 20736 B LDS
#define NCH 4             // 4 chunks x 64 rows = 256 priors per block
#define CNT_STRIDE 32     // pad per-image counters to 128 B (atomic line isolation)
#define FBINS 4096

// ---------------------------------------------------------------------------
// Fast inline f64 exp, degree-9 Taylor after 2-part ln2 reduction.
// |r| <= ln2/2 -> truncation err ~7e-12 rel. Decision-window analysis
// (threshold, rank-1000 gap 5.6e-5, size-filter margin 400x, IoU window)
// shows flips P < ~1e-3 batch-wide. Proven absmax 0.0 in round 13.
// ---------------------------------------------------------------------------
__device__ __forceinline__ double fast_exp(double x)
{
    const double LOG2E = 1.4426950408889634074;
    const double LN2HI = 6.93147180369123816490e-01;
    const double LN2LO = 1.90821492927058770002e-10;
    double nf = rint(x * LOG2E);
    int n = (int)nf;
    double r = fma(-nf, LN2HI, x);
    r = fma(-nf, LN2LO, r);
    double p = 2.7557319223985893e-06;          // 1/9!
    p = fma(p, r, 2.4801587301587302e-05);      // 1/8!
    p = fma(p, r, 1.9841269841269841e-04);      // 1/7!
    p = fma(p, r, 1.3888888888888889e-03);      // 1/6!
    p = fma(p, r, 8.3333333333333332e-03);      // 1/5!
    p = fma(p, r, 4.1666666666666664e-02);      // 1/4!
    p = fma(p, r, 1.6666666666666666e-01);      // 1/3!
    p = fma(p, r, 5.0000000000000000e-01);      // 1/2!
    p = fma(p, r, 1.0);
    p = fma(p, r, 1.0);
    i64 bits = ((i64)(n + 1023)) << 52;         // 2^n (n in [-40, 3] here)
    return p * __longlong_as_double(bits);
}

// ---------------------------------------------------------------------------
// Row-chunked score kernel. Register-cached interleaved rows; size filter
// deduped to wave 0; count phase f32-prefilter only; emit writes dummy
// 0-entries on f64-threshold fail. launch_bounds(256,7): 7 blocks/CU
// (LDS 22KB x 7 = 154KB, VGPR 48 << 512/7).
// ---------------------------------------------------------------------------
__global__ __launch_bounds__(TPB, 7)
void score_kernel(const float* __restrict__ logits, const float* __restrict__ rel,
                  const float* __restrict__ priors, const float* __restrict__ ts,
                  int P, u64* __restrict__ bigCand, u32* __restrict__ bigCnt)
{
    __shared__ float xs[RCH * NCLS];      // 20736 B
    __shared__ double sden[RCH];
    __shared__ float tfl[RCH];
    __shared__ u32 okm[RCH];
    __shared__ u32 wsum[4];
    __shared__ u32 s_base;
    int img = blockIdx.y;
    int p0 = blockIdx.x * TPB;
    int tid = threadIdx.x;
    int lane = tid & 63, wid = tid >> 6;
    int sub = tid & 3;                    // quarter-row lane 0..3
    int rloc = tid >> 2;                  // local row 0..63

    for (int ch = 0; ch < NCH; ++ch) {
        int rbase = p0 + ch * RCH;
        __syncthreads();                  // previous chunk fully consumed
        int nrows = min(RCH, P - rbase);
        if (nrows == RCH) {
            // flat contiguous tile: 64 rows x 81 cols = 1296 float4 (16B-aligned)
            const float4* s4 = (const float4*)(logits + ((size_t)img * P + rbase) * NCLS);
            float4* d4 = (float4*)xs;
#pragma unroll
            for (int k = 0; k < 5; ++k) d4[k * TPB + tid] = s4[k * TPB + tid];
            if (tid < 16) d4[5 * TPB + tid] = s4[5 * TPB + tid];
        } else if (nrows > 0) {
            const float* s1 = logits + ((size_t)img * P + rbase) * NCLS;
            int nflat = nrows * NCLS;
            for (int f = tid; f < nflat; f += TPB) xs[f] = s1[f];
        }
        __syncthreads();

        int p = rbase + rloc;
        bool live = (p < P);
        const float* row = xs + rloc * NCLS;

        // ---- single LDS walk: lane's interleaved classes into registers ----
        float vals[21];
#pragma unroll
        for (int i = 0; i < 21; ++i) {
            int j = sub + 4 * i;
            vals[i] = (live && j < NCLS) ? row[j] : -1.0e30f;
        }

        // ---- max over row (exact): register tree + 4-lane shfl combine ----
        float m = vals[0];
#pragma unroll
        for (int i = 1; i < 21; ++i) m = fmaxf(m, vals[i]);
        m = fmaxf(m, __shfl_xor(m, 1));
        m = fmaxf(m, __shfl_xor(m, 2));

        // ---- f64 denominator from registers + 4-lane tree combine ----
        double md = (double)m;
        double acc = 0.0;
#pragma unroll
        for (int i = 0; i < 21; ++i) {
            if (vals[i] > -1.0e29f)       // skips only pad slots
                acc += fast_exp((double)vals[i] - md);
        }
        acc += __shfl_xor(acc, 1);        // bitwise-identical across the 4 lanes
        acc += __shfl_xor(acc, 2);
        double s = acc;
        if (sub == 0) sden[rloc] = s;
        __syncthreads();

        // ---- size filter: wave 0 only (1 thread per row, coalesced loads) ----
        if (tid < RCH) {                  // wave-uniform: waves 1-3 skip entirely
            int p2 = rbase + tid;
            bool ok2 = false;
            float t2 = 3.4e38f;
            if (p2 < P) {
                double s2 = sden[tid];
                t2 = logf(0.05f * (float)s2) - 3e-4f;   // conservative prefilter
                const float* rp = rel + ((size_t)img * P + p2) * 4;
                const float* pp = priors + (size_t)p2 * 4;
                double pw = pp[2], ph = pp[3];
                double cx = (double)pp[0] + (double)rp[0] * 0.1 * pw;
                double cy = (double)pp[1] + (double)rp[1] * 0.1 * ph;
                double bw = pw * fast_exp((double)rp[2] * 0.2);
                double bh = ph * fast_exp((double)rp[3] * 0.2);
                double sw = (double)ts[img * 2 + 1], sh = (double)ts[img * 2 + 0];
                double x1 = (cx - bw * 0.5) * sw, x2 = (cx + bw * 0.5) * sw;
                double y1 = (cy - bh * 0.5) * sh, y2 = (cy + bh * 0.5) * sh;
                ok2 = (x2 - x1 >= 0.01) && (y2 - y1 >= 0.01);
            }
            okm[tid] = ok2 ? 1u : 0u;
            tfl[tid] = t2;
        }
        __syncthreads();
        bool ok = okm[rloc] != 0;
        float tf_lo = tfl[rloc];

        // ---- count PREFILTER passes only (no f64 here) ----
        u32 cnt = 0;
#pragma unroll
        for (int i = 0; i < 21; ++i) {
            int j = sub + 4 * i;
            if (ok && j != 0 && vals[i] - m > tf_lo) cnt++;   // pads fail df test
        }
        // wave-level inclusive scan, tiny LDS combine, 1 atomic per block/chunk
        u32 inc = cnt;
        for (int off = 1; off < 64; off <<= 1) {
            u32 v = __shfl_up(inc, off);
            if (lane >= off) inc += v;
        }
        if (lane == 63) wsum[wid] = inc;
        __syncthreads();
        if (tid == 0) {
            u32 tot = wsum[0] + wsum[1] + wsum[2] + wsum[3];
            s_base = tot ? atomicAdd(&bigCnt[(size_t)img * CNT_STRIDE], tot) : 0u;
        }
        __syncthreads();
        if (ok && cnt) {
            u32 wbase = 0;
            for (int w = 0; w < wid; ++w) wbase += wsum[w];
            u32 pos = s_base + wbase + inc - cnt;      // exclusive prefix
#pragma unroll
            for (int i = 0; i < 21; ++i) {
                int j = sub + 4 * i;
                if (j != 0 && vals[i] - m > tf_lo) {
                    double e = fast_exp((double)vals[i] - md);
                    double sc = e / s;
                    u64 entry = 0ULL;                  // dummy if threshold fails
                    if (sc > 0.05) {
                        u32 key = __float_as_uint((float)sc) ^ 0x80000000u;
                        u32 idx = (u32)p * 80u + (u32)(j - 1);
                        // sort key: (score desc, idx asc) == u64 desc
                        entry = ((u64)key << 32) | (u64)(u32)(~idx);
                    }
                    if (pos < BIGCAP)
                        bigCand[(size_t)img * BIGCAP + pos] = entry;
                    pos++;
                }
            }
        }
    }
}

// ---------------------------------------------------------------------------
// Fully fused select + NMS + output, one block per image, all-LDS.
// NMS v2: alive bitmap in wave-0 registers (16 lanes x u64); next accepted
// index via ballot+ffs (O(1), no serial LDS scan); suppression masks via
// per-wave ballot (wave w == word w). IoU arithmetic identical to round 13.
// ---------------------------------------------------------------------------
__global__ __launch_bounds__(1024)
void select_nms_kernel(const u64* __restrict__ bigCand, const u32* __restrict__ bigCnt,
                       const float* __restrict__ rel, const float* __restrict__ priors,
                       const float* __restrict__ ts, int P,
                       float* __restrict__ out, int B)
{
    __shared__ u64 smemU[7584];           // 60672 B union
    __shared__ u64 supW16[16];
    __shared__ u32 s_sel, s_run, s_floor, s_cnt;
    __shared__ int s_i;
    int img = blockIdx.x;
    int tid = threadIdx.x;
    int lane = tid & 63;
    int wv = tid >> 6;                    // wave id 0..15 == alive-word id
    u32 bc = bigCnt[(size_t)img * CNT_STRIDE];
    if (bc > (u32)BIGCAP) bc = BIGCAP;
    const u64* src = bigCand + (size_t)img * BIGCAP;

    // ---- phase A layout ----
    u64* s = smemU;                                   // [2048] u64, 16384 B
    u32* h = (u32*)((char*)smemU + 16384);            // [4096] u32, 16384 B

    for (int i = tid; i < FBINS; i += 1024) h[i] = 0;
    if (tid == 0) s_cnt = 0;
    __syncthreads();
    for (u32 k = tid; k < bc; k += 1024) {
        u32 key = (u32)(src[k] >> 32);
        if (key) atomicAdd(&h[key >> 20], 1u);        // dummies (key==0) excluded
    }
    __syncthreads();
    if (tid == 0) {
        u32 run = 0; int d = FBINS - 1;
        for (; d >= 0; --d) {
            if (run + h[d] >= KTOP) break;
            run += h[d];
        }
        s_sel = (u32)d;          // 0xFFFFFFFF if total < KTOP
        s_run = run;
    }
    __syncthreads();
    u32 d12 = s_sel;
    if ((int)d12 >= 0) {
        u32 run0 = s_run;
        if (tid < 16) h[tid] = 0;
        __syncthreads();
        for (u32 k = tid; k < bc; k += 1024) {
            u32 key = (u32)(src[k] >> 32);
            if (key && (key >> 20) == d12) atomicAdd(&h[(key >> 16) & 0xF], 1u);
        }
        __syncthreads();
        if (tid == 0) {
            u32 run = run0;
            int b = 15;
            for (; b >= 0; --b) {
                run += h[b];
                if (run >= KTOP) break;
            }
            if (b < 0) b = 0;
            s_floor = ((d12 << 4) | (u32)b) << 16;
        }
    } else {
        if (tid == 0) s_floor = 0u;
    }
    __syncthreads();
    u32 fkey = s_floor;
    // compact into LDS sort buffer (wave-aggregated LDS atomic)
    for (u32 k0 = 0; k0 < bc; k0 += 1024) {
        u32 k = k0 + tid;
        u64 e = 0; bool pass = false;
        if (k < bc) {
            e = src[k];
            u32 ky = (u32)(e >> 32);
            pass = ky && (ky >= fkey);
        }
        u64 mask = __ballot(pass);
        if (mask) {
            int leader = __ffsll((long long)mask) - 1;
            u32 basePos = 0;
            if (lane == leader) basePos = atomicAdd(&s_cnt, (u32)__popcll(mask));
            basePos = __shfl(basePos, leader);
            if (pass) {
                u32 pos = basePos + (u32)__popcll(mask & ((1ULL << lane) - 1ULL));
                if (pos < CANDCAP) s[pos] = e;
            }
        }
    }
    __syncthreads();
    u32 n = s_cnt; if (n > CANDCAP) n = CANDCAP;
    for (int k = tid; k < CANDCAP; k += 1024)
        if ((u32)k >= n) s[k] = 0ULL;
    __syncthreads();
    // bitonic sort, descending, 2048 entries
    for (u32 len = 2; len <= CANDCAP; len <<= 1) {
        for (u32 j = len >> 1; j > 0; j >>= 1) {
            for (int i = tid; i < CANDCAP; i += 1024) {
                u32 ixj = (u32)i ^ j;
                if (ixj > (u32)i) {
                    u64 a = s[i], b = s[ixj];
                    bool up = ((i & len) == 0);
                    if (up ? (a < b) : (a > b)) { s[i] = b; s[ixj] = a; }
                }
            }
            __syncthreads();
        }
    }

    // ---- capture sorted entries to registers; then repurpose the union ----
    u64 e = (tid < KTOP) ? s[tid] : 0ULL;
    __syncthreads();                      // all s reads done before overwrite

    // ---- phase B layout ----
    double* o0   = (double*)smemU;                          // 1000 d
    double* o1   = (double*)((char*)smemU +  8000);         // 1000 d
    double* o2   = (double*)((char*)smemU + 16000);         // 1000 d
    double* o3   = (double*)((char*)smemU + 24000);         // 1000 d
    double* arA  = (double*)((char*)smemU + 32000);         // 1000 d
    int*    clsA = (int*)   ((char*)smemU + 44000);         // 1000 i32
    float*  scA  = (float*) ((char*)smemU + 48000);         // 1000 f32
    int*    keptS= (int*)   ((char*)smemU + 52000);         // 100 i32
    double* red  = (double*)((char*)smemU + 52416);         // 1024 d

    // decode top-1000 (raw f64 boxes), stage phase-B arrays
    double b0 = 0, b1 = 0, b2 = 0, b3 = 0;
    int cls = 0;
    float score = -1.0f;
    bool validE = (tid < KTOP) && ((e >> 32) != 0ULL);
    double v = -1e300;
    if (tid < KTOP) {
        if (validE) {
            u32 key = (u32)(e >> 32);
            score = __uint_as_float(key ^ 0x80000000u);
            u32 idx = ~((u32)e);
            int p = (int)(idx / 80u), c0 = (int)(idx % 80u);
            cls = c0;
            const float* rp = rel + ((size_t)img * P + p) * 4;
            const float* pp = priors + (size_t)p * 4;
            double pw = pp[2], ph = pp[3];
            double cx = (double)pp[0] + (double)rp[0] * 0.1 * pw;
            double cy = (double)pp[1] + (double)rp[1] * 0.1 * ph;
            double bw = pw * fast_exp((double)rp[2] * 0.2);
            double bh = ph * fast_exp((double)rp[3] * 0.2);
            double sw = (double)ts[img * 2 + 1], sh = (double)ts[img * 2 + 0];
            b0 = (cx - bw * 0.5) * sw; b1 = (cy - bh * 0.5) * sh;
            b2 = (cx + bw * 0.5) * sw; b3 = (cy + bh * 0.5) * sh;
            v = fmax(fmax(b0, b1), fmax(b2, b3));
        } else {
            v = 0.0;                      // invalid -> 0 (where(valid, b, 0))
        }
        o0[tid] = b0; o1[tid] = b1; o2[tid] = b2; o3[tid] = b3;
        clsA[tid] = cls; scA[tid] = score;
        red[tid] = v;
    } else {
        red[tid] = -1e300;
    }
    __syncthreads();
    for (int off = 512; off > 0; off >>= 1) {
        if (tid < off) red[tid] = fmax(red[tid], red[tid + off]);
        __syncthreads();
    }
    double maxc1 = red[0] + 1.0;
    // areas of OFFSET boxes in np's op order (bo = b + off, then diffs)
    if (tid < KTOP) {
        double off_ = (double)cls * maxc1;
        double a0 = b0 + off_, a1 = b1 + off_, a2 = b2 + off_, a3 = b3 + off_;
        arA[tid] = (a2 - a0) * (a3 - a1);
    }
    // build alive bitmap: wave w ballots validity of its j-range (word w)
    u64 wb = __ballot(validE);            // bit (tid&63) = validE of j=tid
    if (lane == 0) supW16[wv] = wb;
    __syncthreads();
    u64 aliveW = (tid < 16) ? supW16[tid] : 0ULL;   // wave-0 lanes own words

    // ---- greedy NMS: O(1) next-alive via ballot/ffs; parallel IoU rows ----
    int cnt = 0;
    while (cnt < DETS) {                  // uniform (cnt, s_i shared)
        if (wv == 0) {                    // find first alive index
            bool has = (lane < 16) && (aliveW != 0ULL);
            u64 bal = __ballot(has);
            int ni = -1;
            if (bal) {
                int w0 = __ffsll((i64)bal) - 1;
                u64 word = __shfl(aliveW, w0);
                int bt = __ffsll((i64)word) - 1;
                ni = w0 * 64 + bt;
            }
            if (lane == 0) s_i = ni;
        }
        __syncthreads();                  // s_i visible; prev supW consumed
        int i = s_i;
        if (i < 0) break;                 // uniform
        if (tid == 0) keptS[cnt] = i;
        cnt++;
        // suppression row for j = tid (recomputed offsets: bit-identical f64)
        double offi = (double)clsA[i] * maxc1;
        double a0 = o0[i] + offi, a1 = o1[i] + offi;
        double a2 = o2[i] + offi, a3 = o3[i] + offi;
        double aA = arA[i];
        bool sup = false;
        if (tid < KTOP && tid > i) {
            double offj = (double)clsA[tid] * maxc1;
            double c0 = o0[tid] + offj, c1 = o1[tid] + offj;
            double c2 = o2[tid] + offj, c3 = o3[tid] + offj;
            double ltx = fmax(a0, c0), lty = fmax(a1, c1);
            double rbx = fmin(a2, c2), rby = fmin(a3, c3);
            double wx = fmax(rbx - ltx, 0.0), wy = fmax(rby - lty, 0.0);
            double inter = wx * wy;
            sup = inter > 0.45 * (((aA + arA[tid]) - inter) + 1e-12);
        }
        u64 ws = __ballot(sup);           // wave w == word w of j-space
        if (lane == 0) supW16[wv] = ws;
        __syncthreads();                  // supW visible to wave 0
        if (tid < 16) {
            aliveW &= ~supW16[tid];
            if (tid == (i >> 6)) aliveW &= ~(1ULL << (i & 63));
        }
        // no barrier needed here: wave 0 consumed supW; other waves only
        // rewrite supW after the next top-of-loop __syncthreads()
    }
    __syncthreads();

    // ---- final top-100 write-out ----
    int r = tid;
    if (r < DETS) {
        float f0 = 0.f, f1 = 0.f, f2 = 0.f, f3 = 0.f, sc = 0.f, lb = -1.0f, vd = 0.f;
        if (r < cnt) {
            int i2 = keptS[r];
            f0 = (float)o0[i2]; f1 = (float)o1[i2];
            f2 = (float)o2[i2]; f3 = (float)o3[i2];
            sc = scA[i2];
            lb = (float)(clsA[i2] + 1);
            vd = 1.0f;
        }
        ((float4*)out)[(size_t)img * DETS + r] = make_float4(f0, f1, f2, f3);
        out[(size_t)B * 400 + (size_t)img * DETS + r] = sc;   // scores
        out[(size_t)B * 500 + (size_t)img * DETS + r] = lb;   // labels (as f32)
        out[(size_t)B * 600 + (size_t)img * DETS + r] = vd;   // valid (as f32)
    }
}

extern "C" void kernel_launch(void* const* d_in, const int* in_sizes, int n_in,
                              void* d_out, int out_size, void* d_ws, size_t ws_size,
                              hipStream_t stream)
{
    const float* logits = (const float*)d_in[0];
    const float* rel    = (const float*)d_in[1];
    const float* priors = (const float*)d_in[2];
    const float* ts     = (const float*)d_in[3];
    float* out = (float*)d_out;
    int P = in_sizes[2] / 4;
    int B = in_sizes[3] / 2;

    char* ws = (char*)d_ws;
    size_t zero_bytes = (size_t)B * CNT_STRIDE * 4;          // bigCnt
    size_t o_big = (zero_bytes + 255) & ~(size_t)255;

    u32* bigCnt  = (u32*)ws;
    u64* bigCand = (u64*)(ws + o_big);

    hipMemsetAsync(ws, 0, zero_bytes, stream);

    dim3 g1((P + TPB - 1) / TPB, B);
    score_kernel<<<g1, TPB, 0, stream>>>(logits, rel, priors, ts, P, bigCand, bigCnt);
    select_nms_kernel<<<B, 1024, 0, stream>>>(bigCand, bigCnt, rel, priors, ts, P,
                                              out, B);
    (void)n_in; (void)out_size; (void)ws_size;
}

// Round 17
// 286.733 us; speedup vs baseline: 1.2288x; 1.2288x over previous
//
#include <hip/hip_runtime.h>
#include <stdint.h>

typedef unsigned int u32;
typedef unsigned long long u64;
typedef long long i64;

#define NCLS 81
#define KTOP 1000
#define DETS 100
#define CANDCAP 2048
#define BIGCAP 131072
#define TPB 256
#define RCH 64            // rows per staging chunk: 64*81*4 = 20736 B LDS
#define NCH 4             // 4 chunks x 64 rows = 256 priors per block
#define CNT_STRIDE 32     // pad per-image counters to 128 B (atomic line isolation)
#define FBINS 4096

// ---------------------------------------------------------------------------
// Reference f64 exp (degree-12, rel err ~1e-15). Used for: table init (32
// calls/block) and select_nms decode (2000 calls/img). Not the hot path.
// ---------------------------------------------------------------------------
__device__ __forceinline__ double exp_ref(double x)
{
    const double LOG2E = 1.4426950408889634074;
    const double LN2HI = 6.93147180369123816490e-01;
    const double LN2LO = 1.90821492927058770002e-10;
    double nf = rint(x * LOG2E);
    int n = (int)nf;
    double r = fma(-nf, LN2HI, x);
    r = fma(-nf, LN2LO, r);
    double p = 2.0876756987868099e-09;
    p = fma(p, r, 2.5052108385441720e-08);
    p = fma(p, r, 2.7557319223985891e-07);
    p = fma(p, r, 2.7557319223985893e-06);
    p = fma(p, r, 2.4801587301587302e-05);
    p = fma(p, r, 1.9841269841269841e-04);
    p = fma(p, r, 1.3888888888888889e-03);
    p = fma(p, r, 8.3333333333333332e-03);
    p = fma(p, r, 4.1666666666666664e-02);
    p = fma(p, r, 1.6666666666666666e-01);
    p = fma(p, r, 5.0000000000000000e-01);
    p = fma(p, r, 1.0);
    p = fma(p, r, 1.0);
    i64 bits = ((i64)(n + 1023)) << 52;
    return p * __longlong_as_double(bits);
}

// ---------------------------------------------------------------------------
// Hot-path f64 exp: 5-bit table reduction. n = rint(x*32/ln2) -> |r| <= ln2/64,
// degree-4 Taylor (err r^5/120 ~ 1.3e-12 rel, BETTER than the proven degree-9's
// 7e-12). 2^(n&31) from 32-entry LDS table; 2^(n>>5) via exponent bits.
// ~9 f64 ops + 1 ds_read_b64 vs 15 f64 ops.
// ---------------------------------------------------------------------------
__device__ __forceinline__ double fexp(double x, const double* __restrict__ etab)
{
    const double L32     = 1.4426950408889634074 * 32.0;          // 32*log2e
    const double LN32HI  = 6.93147180369123816490e-01 / 32.0;     // exact /32
    const double LN32LO  = 1.90821492927058770002e-10 / 32.0;
    double nf = rint(x * L32);
    int n = (int)nf;
    double r = fma(-nf, LN32HI, x);
    r = fma(-nf, LN32LO, r);
    double p = 4.1666666666666664e-02;          // 1/24
    p = fma(p, r, 1.6666666666666666e-01);      // 1/6
    p = fma(p, r, 5.0000000000000000e-01);      // 1/2
    p = fma(p, r, 1.0);
    p = fma(p, r, 1.0);
    double tb = etab[n & 31];
    i64 q = (i64)(n >> 5) + 1023;               // n>>5 floors (arith shift)
    return (p * tb) * __longlong_as_double(q << 52);
}

// ---------------------------------------------------------------------------
// Row-chunked score kernel. Register-cached interleaved rows; size filter
// deduped to wave 0; count phase f32-prefilter only; emit writes dummy
// 0-entries on f64-threshold fail. launch_bounds(256,6): VGPR budget 85
// (>48 used, no spill — the (256,7) budget of 73 spilled vals[21] in r16).
// ---------------------------------------------------------------------------
__global__ __launch_bounds__(TPB, 6)
void score_kernel(const float* __restrict__ logits, const float* __restrict__ rel,
                  const float* __restrict__ priors, const float* __restrict__ ts,
                  int P, u64* __restrict__ bigCand, u32* __restrict__ bigCnt)
{
    __shared__ float xs[RCH * NCLS];      // 20736 B
    __shared__ double etab[32];           // 2^(k/32), k=0..31
    __shared__ double sden[RCH];
    __shared__ float tfl[RCH];
    __shared__ u32 okm[RCH];
    __shared__ u32 wsum[4];
    __shared__ u32 s_base;
    int img = blockIdx.y;
    int p0 = blockIdx.x * TPB;
    int tid = threadIdx.x;
    int lane = tid & 63, wid = tid >> 6;
    int sub = tid & 3;                    // quarter-row lane 0..3
    int rloc = tid >> 2;                  // local row 0..63

    if (tid < 32)
        etab[tid] = exp_ref((double)tid * (6.93147180369123816490e-01 / 32.0));
    // (first use is after the chunk-0 staging barriers below)

    for (int ch = 0; ch < NCH; ++ch) {
        int rbase = p0 + ch * RCH;
        __syncthreads();                  // previous chunk fully consumed
        int nrows = min(RCH, P - rbase);
        if (nrows == RCH) {
            // flat contiguous tile: 64 rows x 81 cols = 1296 float4 (16B-aligned)
            const float4* s4 = (const float4*)(logits + ((size_t)img * P + rbase) * NCLS);
            float4* d4 = (float4*)xs;
#pragma unroll
            for (int k = 0; k < 5; ++k) d4[k * TPB + tid] = s4[k * TPB + tid];
            if (tid < 16) d4[5 * TPB + tid] = s4[5 * TPB + tid];
        } else if (nrows > 0) {
            const float* s1 = logits + ((size_t)img * P + rbase) * NCLS;
            int nflat = nrows * NCLS;
            for (int f = tid; f < nflat; f += TPB) xs[f] = s1[f];
        }
        __syncthreads();

        int p = rbase + rloc;
        bool live = (p < P);
        const float* row = xs + rloc * NCLS;

        // ---- single LDS walk: lane's interleaved classes into registers ----
        float vals[21];
#pragma unroll
        for (int i = 0; i < 21; ++i) {
            int j = sub + 4 * i;
            vals[i] = (live && j < NCLS) ? row[j] : -1.0e30f;
        }

        // ---- max over row (exact): register tree + 4-lane shfl combine ----
        float m = vals[0];
#pragma unroll
        for (int i = 1; i < 21; ++i) m = fmaxf(m, vals[i]);
        m = fmaxf(m, __shfl_xor(m, 1));
        m = fmaxf(m, __shfl_xor(m, 2));

        // ---- f64 denominator from registers + 4-lane tree combine ----
        double md = (double)m;
        double acc = 0.0;
#pragma unroll
        for (int i = 0; i < 21; ++i) {
            if (vals[i] > -1.0e29f)       // skips only pad slots
                acc += fexp((double)vals[i] - md, etab);
        }
        acc += __shfl_xor(acc, 1);        // bitwise-identical across the 4 lanes
        acc += __shfl_xor(acc, 2);
        double s = acc;
        if (sub == 0) sden[rloc] = s;
        __syncthreads();

        // ---- size filter: wave 0 only (1 thread per row, coalesced loads) ----
        if (tid < RCH) {                  // wave-uniform: waves 1-3 skip entirely
            int p2 = rbase + tid;
            bool ok2 = false;
            float t2 = 3.4e38f;
            if (p2 < P) {
                double s2 = sden[tid];
                t2 = logf(0.05f * (float)s2) - 3e-4f;   // conservative prefilter
                const float* rp = rel + ((size_t)img * P + p2) * 4;
                const float* pp = priors + (size_t)p2 * 4;
                double pw = pp[2], ph = pp[3];
                double cx = (double)pp[0] + (double)rp[0] * 0.1 * pw;
                double cy = (double)pp[1] + (double)rp[1] * 0.1 * ph;
                double bw = pw * fexp((double)rp[2] * 0.2, etab);
                double bh = ph * fexp((double)rp[3] * 0.2, etab);
                double sw = (double)ts[img * 2 + 1], sh = (double)ts[img * 2 + 0];
                double x1 = (cx - bw * 0.5) * sw, x2 = (cx + bw * 0.5) * sw;
                double y1 = (cy - bh * 0.5) * sh, y2 = (cy + bh * 0.5) * sh;
                ok2 = (x2 - x1 >= 0.01) && (y2 - y1 >= 0.01);
            }
            okm[tid] = ok2 ? 1u : 0u;
            tfl[tid] = t2;
        }
        __syncthreads();
        bool ok = okm[rloc] != 0;
        float tf_lo = tfl[rloc];

        // ---- count PREFILTER passes only (no f64 here) ----
        u32 cnt = 0;
#pragma unroll
        for (int i = 0; i < 21; ++i) {
            int j = sub + 4 * i;
            if (ok && j != 0 && vals[i] - m > tf_lo) cnt++;   // pads fail df test
        }
        // wave-level inclusive scan, tiny LDS combine, 1 atomic per block/chunk
        u32 inc = cnt;
        for (int off = 1; off < 64; off <<= 1) {
            u32 v = __shfl_up(inc, off);
            if (lane >= off) inc += v;
        }
        if (lane == 63) wsum[wid] = inc;
        __syncthreads();
        if (tid == 0) {
            u32 tot = wsum[0] + wsum[1] + wsum[2] + wsum[3];
            s_base = tot ? atomicAdd(&bigCnt[(size_t)img * CNT_STRIDE], tot) : 0u;
        }
        __syncthreads();
        if (ok && cnt) {
            u32 wbase = 0;
            for (int w = 0; w < wid; ++w) wbase += wsum[w];
            u32 pos = s_base + wbase + inc - cnt;      // exclusive prefix
#pragma unroll
            for (int i = 0; i < 21; ++i) {
                int j = sub + 4 * i;
                if (j != 0 && vals[i] - m > tf_lo) {
                    double e = fexp((double)vals[i] - md, etab);
                    double sc = e / s;
                    u64 entry = 0ULL;                  // dummy if threshold fails
                    if (sc > 0.05) {
                        u32 key = __float_as_uint((float)sc) ^ 0x80000000u;
                        u32 idx = (u32)p * 80u + (u32)(j - 1);
                        // sort key: (score desc, idx asc) == u64 desc
                        entry = ((u64)key << 32) | (u64)(u32)(~idx);
                    }
                    if (pos < BIGCAP)
                        bigCand[(size_t)img * BIGCAP + pos] = entry;
                    pos++;
                }
            }
        }
    }
}

// ---------------------------------------------------------------------------
// Fully fused select + NMS + output, one block per image, all-LDS.
// Floor scan v2: 1024-thread suffix scan over the 4096-bin hist + atomicMax
// group locate + 4-bin serial finish (replaces the ~1000-iter single-thread
// scan; identical semantics: largest d with suffix>=KTOP, run = suffix above).
// NMS: alive bitmap in wave-0 registers, ballot+ffs next-alive (proven r16).
// ---------------------------------------------------------------------------
__global__ __launch_bounds__(1024)
void select_nms_kernel(const u64* __restrict__ bigCand, const u32* __restrict__ bigCnt,
                       const float* __restrict__ rel, const float* __restrict__ priors,
                       const float* __restrict__ ts, int P,
                       float* __restrict__ out, int B)
{
    __shared__ u64 smemU[7584];           // 60672 B union
    __shared__ u64 supW16[16];
    __shared__ u32 s_sel, s_run, s_floor, s_cnt;
    __shared__ int s_i, s_t;
    int img = blockIdx.x;
    int tid = threadIdx.x;
    int lane = tid & 63;
    int wv = tid >> 6;                    // wave id 0..15 == alive-word id
    u32 bc = bigCnt[(size_t)img * CNT_STRIDE];
    if (bc > (u32)BIGCAP) bc = BIGCAP;
    const u64* src = bigCand + (size_t)img * BIGCAP;

    // ---- phase A layout ----
    u64* s    = smemU;                                // [2048] u64, 16384 B
    u32* h    = (u32*)((char*)smemU + 16384);         // [4096] u32, 16384 B
    u32* tsum = (u32*)((char*)smemU + 32768);         // [1024] u32,  4096 B

    for (int i = tid; i < FBINS; i += 1024) h[i] = 0;
    if (tid == 0) { s_cnt = 0; s_t = -1; }
    __syncthreads();
    for (u32 k = tid; k < bc; k += 1024) {
        u32 key = (u32)(src[k] >> 32);
        if (key) atomicAdd(&h[key >> 20], 1u);        // dummies (key==0) excluded
    }
    __syncthreads();
    // parallel suffix scan: tsum[t] = sum of bins 4t..4095
    tsum[tid] = h[tid * 4] + h[tid * 4 + 1] + h[tid * 4 + 2] + h[tid * 4 + 3];
    __syncthreads();
    for (int off = 1; off < 1024; off <<= 1) {
        u32 v = (tid + off < 1024) ? tsum[tid + off] : 0u;
        __syncthreads();
        tsum[tid] += v;
        __syncthreads();
    }
    if (tsum[tid] >= KTOP) atomicMax(&s_t, tid);      // largest group w/ suffix>=K
    __syncthreads();
    int t_star = s_t;
    if (t_star >= 0) {
        if (tid == t_star) {
            u32 run = (t_star + 1 < 1024) ? tsum[t_star + 1] : 0u;
            int d = 4 * t_star + 3;
            for (; d >= 4 * t_star; --d) {            // guaranteed hit in group
                if (run + h[d] >= KTOP) break;
                run += h[d];
            }
            s_sel = (u32)d;
            s_run = run;
        }
    } else {
        if (tid == 0) s_sel = 0xFFFFFFFFu;            // total < KTOP
    }
    __syncthreads();
    u32 d12 = s_sel;
    if ((int)d12 >= 0) {
        u32 run0 = s_run;
        if (tid < 16) h[tid] = 0;
        __syncthreads();
        for (u32 k = tid; k < bc; k += 1024) {
            u32 key = (u32)(src[k] >> 32);
            if (key && (key >> 20) == d12) atomicAdd(&h[(key >> 16) & 0xF], 1u);
        }
        __syncthreads();
        if (tid == 0) {
            u32 run = run0;
            int b = 15;
            for (; b >= 0; --b) {
                run += h[b];
                if (run >= KTOP) break;
            }
            if (b < 0) b = 0;
            s_floor = ((d12 << 4) | (u32)b) << 16;
        }
    } else {
        if (tid == 0) s_floor = 0u;
    }
    __syncthreads();
    u32 fkey = s_floor;
    // compact into LDS sort buffer (wave-aggregated LDS atomic)
    for (u32 k0 = 0; k0 < bc; k0 += 1024) {
        u32 k = k0 + tid;
        u64 e = 0; bool pass = false;
        if (k < bc) {
            e = src[k];
            u32 ky = (u32)(e >> 32);
            pass = ky && (ky >= fkey);
        }
        u64 mask = __ballot(pass);
        if (mask) {
            int leader = __ffsll((long long)mask) - 1;
            u32 basePos = 0;
            if (lane == leader) basePos = atomicAdd(&s_cnt, (u32)__popcll(mask));
            basePos = __shfl(basePos, leader);
            if (pass) {
                u32 pos = basePos + (u32)__popcll(mask & ((1ULL << lane) - 1ULL));
                if (pos < CANDCAP) s[pos] = e;
            }
        }
    }
    __syncthreads();
    u32 n = s_cnt; if (n > CANDCAP) n = CANDCAP;
    for (int k = tid; k < CANDCAP; k += 1024)
        if ((u32)k >= n) s[k] = 0ULL;
    __syncthreads();
    // bitonic sort, descending, 2048 entries
    for (u32 len = 2; len <= CANDCAP; len <<= 1) {
        for (u32 j = len >> 1; j > 0; j >>= 1) {
            for (int i = tid; i < CANDCAP; i += 1024) {
                u32 ixj = (u32)i ^ j;
                if (ixj > (u32)i) {
                    u64 a = s[i], b = s[ixj];
                    bool up = ((i & len) == 0);
                    if (up ? (a < b) : (a > b)) { s[i] = b; s[ixj] = a; }
                }
            }
            __syncthreads();
        }
    }

    // ---- capture sorted entries to registers; then repurpose the union ----
    u64 e = (tid < KTOP) ? s[tid] : 0ULL;
    __syncthreads();                      // all s reads done before overwrite

    // ---- phase B layout ----
    double* o0   = (double*)smemU;                          // 1000 d
    double* o1   = (double*)((char*)smemU +  8000);         // 1000 d
    double* o2   = (double*)((char*)smemU + 16000);         // 1000 d
    double* o3   = (double*)((char*)smemU + 24000);         // 1000 d
    double* arA  = (double*)((char*)smemU + 32000);         // 1000 d
    int*    clsA = (int*)   ((char*)smemU + 44000);         // 1000 i32
    float*  scA  = (float*) ((char*)smemU + 48000);         // 1000 f32
    int*    keptS= (int*)   ((char*)smemU + 52000);         // 100 i32
    double* red  = (double*)((char*)smemU + 52416);         // 1024 d

    // decode top-1000 (raw f64 boxes), stage phase-B arrays
    double b0 = 0, b1 = 0, b2 = 0, b3 = 0;
    int cls = 0;
    float score = -1.0f;
    bool validE = (tid < KTOP) && ((e >> 32) != 0ULL);
    double v = -1e300;
    if (tid < KTOP) {
        if (validE) {
            u32 key = (u32)(e >> 32);
            score = __uint_as_float(key ^ 0x80000000u);
            u32 idx = ~((u32)e);
            int p = (int)(idx / 80u), c0 = (int)(idx % 80u);
            cls = c0;
            const float* rp = rel + ((size_t)img * P + p) * 4;
            const float* pp = priors + (size_t)p * 4;
            double pw = pp[2], ph = pp[3];
            double cx = (double)pp[0] + (double)rp[0] * 0.1 * pw;
            double cy = (double)pp[1] + (double)rp[1] * 0.1 * ph;
            double bw = pw * exp_ref((double)rp[2] * 0.2);
            double bh = ph * exp_ref((double)rp[3] * 0.2);
            double sw = (double)ts[img * 2 + 1], sh = (double)ts[img * 2 + 0];
            b0 = (cx - bw * 0.5) * sw; b1 = (cy - bh * 0.5) * sh;
            b2 = (cx + bw * 0.5) * sw; b3 = (cy + bh * 0.5) * sh;
            v = fmax(fmax(b0, b1), fmax(b2, b3));
        } else {
            v = 0.0;                      // invalid -> 0 (where(valid, b, 0))
        }
        o0[tid] = b0; o1[tid] = b1; o2[tid] = b2; o3[tid] = b3;
        clsA[tid] = cls; scA[tid] = score;
        red[tid] = v;
    } else {
        red[tid] = -1e300;
    }
    __syncthreads();
    for (int off = 512; off > 0; off >>= 1) {
        if (tid < off) red[tid] = fmax(red[tid], red[tid + off]);
        __syncthreads();
    }
    double maxc1 = red[0] + 1.0;
    // areas of OFFSET boxes in np's op order (bo = b + off, then diffs)
    if (tid < KTOP) {
        double off_ = (double)cls * maxc1;
        double a0 = b0 + off_, a1 = b1 + off_, a2 = b2 + off_, a3 = b3 + off_;
        arA[tid] = (a2 - a0) * (a3 - a1);
    }
    // build alive bitmap: wave w ballots validity of its j-range (word w)
    u64 wb = __ballot(validE);            // bit (tid&63) = validE of j=tid
    if (lane == 0) supW16[wv] = wb;
    __syncthreads();
    u64 aliveW = (tid < 16) ? supW16[tid] : 0ULL;   // wave-0 lanes own words

    // ---- greedy NMS: O(1) next-alive via ballot/ffs; parallel IoU rows ----
    int cnt = 0;
    while (cnt < DETS) {                  // uniform (cnt, s_i shared)
        if (wv == 0) {                    // find first alive index
            bool has = (lane < 16) && (aliveW != 0ULL);
            u64 bal = __ballot(has);
            int ni = -1;
            if (bal) {
                int w0 = __ffsll((i64)bal) - 1;
                u64 word = __shfl(aliveW, w0);
                int bt = __ffsll((i64)word) - 1;
                ni = w0 * 64 + bt;
            }
            if (lane == 0) s_i = ni;
        }
        __syncthreads();                  // s_i visible; prev supW consumed
        int i = s_i;
        if (i < 0) break;                 // uniform
        if (tid == 0) keptS[cnt] = i;
        cnt++;
        // suppression row for j = tid (recomputed offsets: bit-identical f64)
        double offi = (double)clsA[i] * maxc1;
        double a0 = o0[i] + offi, a1 = o1[i] + offi;
        double a2 = o2[i] + offi, a3 = o3[i] + offi;
        double aA = arA[i];
        bool sup = false;
        if (tid < KTOP && tid > i) {
            double offj = (double)clsA[tid] * maxc1;
            double c0 = o0[tid] + offj, c1 = o1[tid] + offj;
            double c2 = o2[tid] + offj, c3 = o3[tid] + offj;
            double ltx = fmax(a0, c0), lty = fmax(a1, c1);
            double rbx = fmin(a2, c2), rby = fmin(a3, c3);
            double wx = fmax(rbx - ltx, 0.0), wy = fmax(rby - lty, 0.0);
            double inter = wx * wy;
            sup = inter > 0.45 * (((aA + arA[tid]) - inter) + 1e-12);
        }
        u64 ws = __ballot(sup);           // wave w == word w of j-space
        if (lane == 0) supW16[wv] = ws;
        __syncthreads();                  // supW visible to wave 0
        if (tid < 16) {
            aliveW &= ~supW16[tid];
            if (tid == (i >> 6)) aliveW &= ~(1ULL << (i & 63));
        }
        // no barrier needed here: wave 0 consumed supW; other waves only
        // rewrite supW after the next top-of-loop __syncthreads()
    }
    __syncthreads();

    // ---- final top-100 write-out ----
    int r = tid;
    if (r < DETS) {
        float f0 = 0.f, f1 = 0.f, f2 = 0.f, f3 = 0.f, sc = 0.f, lb = -1.0f, vd = 0.f;
        if (r < cnt) {
            int i2 = keptS[r];
            f0 = (float)o0[i2]; f1 = (float)o1[i2];
            f2 = (float)o2[i2]; f3 = (float)o3[i2];
            sc = scA[i2];
            lb = (float)(clsA[i2] + 1);
            vd = 1.0f;
        }
        ((float4*)out)[(size_t)img * DETS + r] = make_float4(f0, f1, f2, f3);
        out[(size_t)B * 400 + (size_t)img * DETS + r] = sc;   // scores
        out[(size_t)B * 500 + (size_t)img * DETS + r] = lb;   // labels (as f32)
        out[(size_t)B * 600 + (size_t)img * DETS + r] = vd;   // valid (as f32)
    }
}

extern "C" void kernel_launch(void* const* d_in, const int* in_sizes, int n_in,
                              void* d_out, int out_size, void* d_ws, size_t ws_size,
                              hipStream_t stream)
{
    const float* logits = (const float*)d_in[0];
    const float* rel    = (const float*)d_in[1];
    const float* priors = (const float*)d_in[2];
    const float* ts     = (const float*)d_in[3];
    float* out = (float*)d_out;
    int P = in_sizes[2] / 4;
    int B = in_sizes[3] / 2;

    char* ws = (char*)d_ws;
    size_t zero_bytes = (size_t)B * CNT_STRIDE * 4;          // bigCnt
    size_t o_big = (zero_bytes + 255) & ~(size_t)255;

    u32* bigCnt  = (u32*)ws;
    u64* bigCand = (u64*)(ws + o_big);

    hipMemsetAsync(ws, 0, zero_bytes, stream);

    dim3 g1((P + TPB - 1) / TPB, B);
    score_kernel<<<g1, TPB, 0, stream>>>(logits, rel, priors, ts, P, bigCand, bigCnt);
    select_nms_kernel<<<B, 1024, 0, stream>>>(bigCand, bigCnt, rel, priors, ts, P,
                                              out, B);
    (void)n_in; (void)out_size; (void)ws_size;
}